// Round 21
// baseline (142.166 us; speedup 1.0000x reference)
//
#include <hip/hip_runtime.h>

#define T_N   1024
#define B_N   64
#define CIN   32
#define COUT  32
#define MODES 16
#define DT    0.01f
#define PI_F  3.14159265358979323846f
#define W_SCALE 0.613592315154256f   /* 2*pi/(T_N*DT) */
#define W_NYQ  (-314.1592653589793f) /* -pi/DT */

typedef short bf16x8 __attribute__((ext_vector_type(8)));
typedef float f32x4 __attribute__((ext_vector_type(4)));

__device__ __forceinline__ float fastrcp(float x) {
    float r;
    asm("v_rcp_f32 %0, %1" : "=v"(r) : "v"(x));
    return r;
}

// cheap split: truncate hi, truncate lo (pair error <= 2^-16 rel)
__device__ __forceinline__ void bfsplit(float v, short* ph, short* pl) {
    unsigned int u = __float_as_uint(v);
    float lo = v - __uint_as_float(u & 0xFFFF0000u);
    *ph = (short)(u >> 16);
    *pl = (short)(__float_as_uint(lo) >> 16);
}

// ---------------------------------------------------------------------------
// Radix-4 Stockham FFT, length 1024, 5 stages, LDS twiddle table (1024 ent).
// ---------------------------------------------------------------------------
template <int SIGN>
__device__ __forceinline__ float2* fft1024_r4(float2* A, float2* B,
                                              const float2* TW, int tid) {
    float2* src = A;
    float2* dst = B;
    int m = 1;
#pragma unroll
    for (int s = 0; s < 5; ++s) {
        __syncthreads();
        int k  = tid & (m - 1);
        int jm = tid - k;                       // j*m
        float2 a = src[tid];
        float2 b = src[tid + 256];
        float2 c = src[tid + 512];
        float2 d = src[tid + 768];
        float2 t0 = make_float2(a.x + c.x, a.y + c.y);
        float2 t1 = make_float2(a.x - c.x, a.y - c.y);
        float2 t2 = make_float2(b.x + d.x, b.y + d.y);
        float2 t3 = make_float2(b.x - d.x, b.y - d.y);
        float2 it3 = (SIGN == 1) ? make_float2(-t3.y, t3.x)
                                 : make_float2(t3.y, -t3.x);
        float2 y0 = make_float2(t0.x + t2.x, t0.y + t2.y);
        float2 y2 = make_float2(t0.x - t2.x, t0.y - t2.y);
        float2 y1 = make_float2(t1.x + it3.x, t1.y + it3.y);
        float2 y3 = make_float2(t1.x - it3.x, t1.y - it3.y);
        float2 w1 = TW[jm];
        float2 w2 = TW[2 * jm];
        float2 w3 = TW[3 * jm];
        int ob = k + 4 * jm;
        dst[ob] = y0;
        dst[ob + m]     = make_float2(w1.x * y1.x - w1.y * y1.y,
                                      w1.x * y1.y + w1.y * y1.x);
        dst[ob + 2 * m] = make_float2(w2.x * y2.x - w2.y * y2.y,
                                      w2.x * y2.y + w2.y * y2.x);
        dst[ob + 3 * m] = make_float2(w3.x * y3.x - w3.y * y3.y,
                                      w3.x * y3.y + w3.y * y3.x);
        float2* t = src; src = dst; dst = t;
        m <<= 2;
    }
    __syncthreads();
    return src;
}

template <int SIGN>
__device__ __forceinline__ void build_tw4(float2* TW, int tid) {
#pragma unroll
    for (int r = 0; r < 4; ++r) {
        int a = tid + (r << 8);                 // 0..1023
        float sn, cs;
        __sincosf((float)SIGN * PI_F * (float)a * (1.0f / 512.0f), &sn, &cs);
        TW[a] = make_float2(cs, sn);
    }
}

// ---------------------------------------------------------------------------
// forward FFT + fused split-bf16 conversion + (blocks 0-63) pol4 pack.
// ---------------------------------------------------------------------------
__global__ __launch_bounds__(256) void k_fft_fwd(const float* __restrict__ x,
                                                 float2* __restrict__ alpha,
                                                 short* __restrict__ aHi,
                                                 short* __restrict__ aLo,
                                                 const float* __restrict__ pr,
                                                 const float* __restrict__ pim,
                                                 const float* __restrict__ rr,
                                                 const float* __restrict__ ri,
                                                 float4* __restrict__ pol4) {
    __shared__ float2 A[1024];
    __shared__ float2 Bb[1024];
    __shared__ float2 TW[1024];
    int row = blockIdx.x;
    int tid = threadIdx.x;
    build_tw4<-1>(TW, tid);
    const float* xr = x + (size_t)row * T_N;
#pragma unroll
    for (int r = 0; r < 4; ++r) {
        int j = tid + (r << 8);
        A[j] = make_float2(xr[j], 0.0f);
    }
    float2* R = fft1024_r4<-1>(A, Bb, TW, tid);
    float2* outp = alpha + (size_t)row * T_N;
#pragma unroll
    for (int r = 0; r < 4; ++r) {
        int j = tid + (r << 8);
        outp[j] = R[j];
    }
    size_t base = (size_t)row * 1024;
#pragma unroll
    for (int rr_ = 0; rr_ < 2; ++rr_) {
        int xj = tid + (rr_ << 8);        // 0..511
        float2 v = R[xj];
        float aR = v.x;
        float aI = (xj == 0) ? R[512].x : v.y;
        short h0, l0, h1, l1;
        bfsplit(aR, &h0, &l0);
        bfsplit(aI, &h1, &l1);
        aHi[base + xj * 2]     = h0;
        aHi[base + xj * 2 + 1] = h1;
        aLo[base + xj * 2]     = l0;
        aLo[base + xj * 2 + 1] = l1;
    }
    if (row < 64) {
        int idx = row * 256 + tid;
        pol4[idx] = make_float4(pr[idx], pim[idx], rr[idx], ri[idx]);
    }
}

// ---------------------------------------------------------------------------
// fused triple kernel:
//   blocks [0,1024):     transpose alpha -> packed bf16 aT[i][x][b]
//   blocks [1024,1280):  Hw table hw[x][i*32+o]
//   blocks [1280,2304):  out2 MFMA -> partial[chunk=(i*2+xh)][b][n]
// All three depend only on k_fft_fwd outputs; disjoint inputs/outputs.
// LDS overlay: max(16.9KB transpose, 21.0KB out2m) = 21.0KB.
// ---------------------------------------------------------------------------
#define ABROW 40   /* shorts per LDS row: 32 data + 8 pad (80B) */
__global__ __launch_bounds__(256) void k_thw_out2m(const float2* __restrict__ alpha,
                                                   unsigned int* __restrict__ aThU,
                                                   unsigned int* __restrict__ aTlU,
                                                   const float4* __restrict__ pol4,
                                                   float2* __restrict__ hw,
                                                   const short* __restrict__ aHi,
                                                   const short* __restrict__ aLo,
                                                   const float* __restrict__ pr,
                                                   const float* __restrict__ pim,
                                                   const float* __restrict__ rr,
                                                   const float* __restrict__ ri,
                                                   float* __restrict__ partial) {
    __shared__ __align__(16) char SMEM[20992];
    int bid = blockIdx.x;
    int tid = threadIdx.x;

    if (bid < 1024) {
        // ---- transpose path ----
        float2* T = (float2*)SMEM;             // 32*66 float2 = 16896 B
        int i = bid >> 5, xt = bid & 31;
#pragma unroll
        for (int r = 0; r < 8; ++r) {
            int e = tid + (r << 8);
            int xx = e & 31, b = e >> 5;
            T[xx * 66 + b] = alpha[((size_t)(b * CIN + i)) * T_N + xt * 32 + xx];
        }
        __syncthreads();
#pragma unroll
        for (int r = 0; r < 8; ++r) {
            int e = tid + (r << 8);
            int b = e & 63, xx = e >> 6;
            float2 v = T[xx * 66 + b];
            short hR, lR, hI, lI;
            bfsplit(v.x, &hR, &lR);
            bfsplit(v.y, &hI, &lI);
            size_t idx = ((size_t)i * T_N + xt * 32 + xx) * B_N + b;
            aThU[idx] = (unsigned int)(unsigned short)hR |
                        ((unsigned int)(unsigned short)hI << 16);
            aTlU[idx] = (unsigned int)(unsigned short)lR |
                        ((unsigned int)(unsigned short)lI << 16);
        }
        return;
    }
    if (bid < 1280) {
        // ---- Hw path ----
        int xb = bid - 1024;
        int io0 = tid * 4;
        float wv[4];
#pragma unroll
        for (int xi = 0; xi < 4; ++xi) {
            int xg = xb * 4 + xi;
            int fx = xg - ((xg >= 512) ? 1024 : 0);
            wv[xi] = (float)fx * W_SCALE;
        }
        float accR[4][4], accI[4][4];
#pragma unroll
        for (int j = 0; j < 4; ++j) {
            const float4* pp = pol4 + (io0 + j) * 16;
            float4 p[16];
#pragma unroll
            for (int k = 0; k < 16; ++k) p[k] = pp[k];
#pragma unroll
            for (int xi = 0; xi < 4; ++xi) {
                float hr = 0.f, hi = 0.f;
#pragma unroll
                for (int k = 0; k < 16; ++k) {
                    float a = p[k].x, bI = p[k].y;
                    float d = wv[xi] - bI;
                    float inv = fastrcp(fmaf(d, d, a * a));
                    float vR = -a * inv, vI = -d * inv;
                    hr += p[k].z * vR - p[k].w * vI;
                    hi += p[k].z * vI + p[k].w * vR;
                }
                accR[xi][j] = hr;
                accI[xi][j] = hi;
            }
        }
#pragma unroll
        for (int xi = 0; xi < 4; ++xi) {
            float4* dst = (float4*)(hw + (size_t)(xb * 4 + xi) * 1024 + io0);
            dst[0] = make_float4(accR[xi][0], accI[xi][0], accR[xi][1], accI[xi][1]);
            dst[1] = make_float4(accR[xi][2], accI[xi][2], accR[xi][3], accI[xi][3]);
        }
        return;
    }

    // ---- out2 MFMA path ----
    short* sAh = (short*)SMEM;                 // 2560 shorts each
    short* sAl = sAh + 64 * ABROW;
    short* sBh = sAl + 64 * ABROW;
    short* sBl = sBh + 64 * ABROW;             // ends at 20480 B
    float* sPol = (float*)(SMEM + 20480);      // 4*32 floats -> 20992 B

    int idx2 = bid - 1280;                     // 0..1023
    const int nb = idx2 & 15, xh = (idx2 >> 4) & 1, i = idx2 >> 5;
    const int w = tid >> 6, l = tid & 63;
    const int r = l & 15, hg = l >> 4;

    if (tid < 32) {
        int o = nb * 2 + (tid >> 4), k = tid & 15;
        int pidx = (i * COUT + o) * MODES + k;
        sPol[0 * 32 + tid] = pr[pidx]; sPol[1 * 32 + tid] = pim[pidx];
        sPol[2 * 32 + tid] = rr[pidx]; sPol[3 * 32 + tid] = ri[pidx];
    }
    __syncthreads();

    f32x4 acc0 = {0.f, 0.f, 0.f, 0.f};
    f32x4 acc1 = {0.f, 0.f, 0.f, 0.f};
    f32x4 acc2 = {0.f, 0.f, 0.f, 0.f};
    f32x4 acc3 = {0.f, 0.f, 0.f, 0.f};

    const int sb = tid >> 2;
    const int sc = (tid & 3) * 8;
    const size_t abase = ((size_t)sb * CIN + i) * 1024 + (size_t)xh * 512;

    const int bn = tid & 63, bh = tid >> 6;
    const int bok = bn >> 1, bcomp = bn & 1;
    const float pa = sPol[0 * 32 + bok], pb = sPol[1 * 32 + bok];
    const float prr_ = sPol[2 * 32 + bok], pri_ = sPol[3 * 32 + bok];
    const float K_d  = pa * pa - pb * pb;
    const float mKe  = -2.0f * pa * pb;
    const float K_e2 = (2.0f * pa * pb) * (2.0f * pa * pb);
    const float prx2 = 2.0f * (pa * prr_ - pb * pri_);
    const float piy2 = 2.0f * (pa * pri_ + pb * prr_);
    const float A1 = bcomp ? piy2 : prx2;
    const float B1 = bcomp ? prx2 : -piy2;
    const float A2 = bcomp ? pri_ : prr_;
    const float B2 = bcomp ? prr_ : -pri_;

    for (int ks = 0; ks < 16; ++ks) {
        __syncthreads();
        *(float4*)&sAh[sb * ABROW + sc] = *(const float4*)&aHi[abase + ks * 32 + sc];
        *(float4*)&sAl[sb * ABROW + sc] = *(const float4*)&aLo[abase + ks * 32 + sc];
        {
            bf16x8 vh, vl;
#pragma unroll
            for (int j4 = 0; j4 < 4; ++j4) {
                int xl = bh * 4 + j4;
                int xg = xh * 256 + ks * 16 + xl;
                float v1, v2;
                if (xg == 0) {
                    float s1 = pa * pa + pb * pb;
                    float q1r = pa / s1, q1i = -pb / s1;
                    float c1r = prr_ * q1r - pri_ * q1i;
                    float c1i = prr_ * q1i + pri_ * q1r;
                    float dr = -pa, di = W_NYQ - pb;
                    float s2 = dr * dr + di * di;
                    float q2r = dr / s2, q2i = -di / s2;
                    float c2r = -(prr_ * q2r - pri_ * q2i);
                    float c2i = -(prr_ * q2i + pri_ * q2r);
                    v1 = bcomp ? c1i : c1r;
                    v2 = bcomp ? c2i : c2r;
                } else {
                    float wv = (float)xg * W_SCALE;
                    float denr = fmaf(wv, wv, K_d);
                    float s = fmaf(denr, denr, K_e2);
                    float inv = fastrcp(s);
                    float qr = denr * inv, qi = mKe * inv;
                    v1 = A1 * qr + B1 * qi;
                    float rq = A2 * qr + B2 * qi;
                    v2 = -2.0f * wv * rq;
                }
                short h1, l1, h2, l2;
                bfsplit(v1, &h1, &l1);
                bfsplit(v2, &h2, &l2);
                vh[j4 * 2] = h1; vh[j4 * 2 + 1] = h2;
                vl[j4 * 2] = l1; vl[j4 * 2 + 1] = l2;
            }
            *(bf16x8*)&sBh[bn * ABROW + bh * 8] = vh;
            *(bf16x8*)&sBl[bn * ABROW + bh * 8] = vl;
        }
        __syncthreads();

        bf16x8 bhf = *(bf16x8*)&sBh[(w * 16 + r) * ABROW + hg * 8];
        bf16x8 blf = *(bf16x8*)&sBl[(w * 16 + r) * ABROW + hg * 8];
        {
            bf16x8 ah = *(bf16x8*)&sAh[(0 * 16 + r) * ABROW + hg * 8];
            bf16x8 al = *(bf16x8*)&sAl[(0 * 16 + r) * ABROW + hg * 8];
            acc0 = __builtin_amdgcn_mfma_f32_16x16x32_bf16(ah, bhf, acc0, 0, 0, 0);
            acc0 = __builtin_amdgcn_mfma_f32_16x16x32_bf16(al, bhf, acc0, 0, 0, 0);
            acc0 = __builtin_amdgcn_mfma_f32_16x16x32_bf16(ah, blf, acc0, 0, 0, 0);
        }
        {
            bf16x8 ah = *(bf16x8*)&sAh[(1 * 16 + r) * ABROW + hg * 8];
            bf16x8 al = *(bf16x8*)&sAl[(1 * 16 + r) * ABROW + hg * 8];
            acc1 = __builtin_amdgcn_mfma_f32_16x16x32_bf16(ah, bhf, acc1, 0, 0, 0);
            acc1 = __builtin_amdgcn_mfma_f32_16x16x32_bf16(al, bhf, acc1, 0, 0, 0);
            acc1 = __builtin_amdgcn_mfma_f32_16x16x32_bf16(ah, blf, acc1, 0, 0, 0);
        }
        {
            bf16x8 ah = *(bf16x8*)&sAh[(2 * 16 + r) * ABROW + hg * 8];
            bf16x8 al = *(bf16x8*)&sAl[(2 * 16 + r) * ABROW + hg * 8];
            acc2 = __builtin_amdgcn_mfma_f32_16x16x32_bf16(ah, bhf, acc2, 0, 0, 0);
            acc2 = __builtin_amdgcn_mfma_f32_16x16x32_bf16(al, bhf, acc2, 0, 0, 0);
            acc2 = __builtin_amdgcn_mfma_f32_16x16x32_bf16(ah, blf, acc2, 0, 0, 0);
        }
        {
            bf16x8 ah = *(bf16x8*)&sAh[(3 * 16 + r) * ABROW + hg * 8];
            bf16x8 al = *(bf16x8*)&sAl[(3 * 16 + r) * ABROW + hg * 8];
            acc3 = __builtin_amdgcn_mfma_f32_16x16x32_bf16(ah, bhf, acc3, 0, 0, 0);
            acc3 = __builtin_amdgcn_mfma_f32_16x16x32_bf16(al, bhf, acc3, 0, 0, 0);
            acc3 = __builtin_amdgcn_mfma_f32_16x16x32_bf16(ah, blf, acc3, 0, 0, 0);
        }
    }

    int chunk = i * 2 + xh;
    int n = nb * 64 + w * 16 + r;
    float* dst = partial + (size_t)chunk * (B_N * 1024) + n;
#pragma unroll
    for (int reg = 0; reg < 4; ++reg) {
        dst[(0 * 16 + hg * 4 + reg) * 1024] = acc0[reg];
        dst[(1 * 16 + hg * 4 + reg) * 1024] = acc1[reg];
        dst[(2 * 16 + hg * 4 + reg) * 1024] = acc2[reg];
        dst[(3 * 16 + hg * 4 + reg) * 1024] = acc3[reg];
    }
}

// ---------------------------------------------------------------------------
// fused: blocks [0,1024): out1 (alpha-slice MAC vs hw row)
//        blocks [1024,1088): reduce 64 partials -> split-bf16 aXh/aXl
// ---------------------------------------------------------------------------
__global__ __launch_bounds__(256) void k_out1_reduce(const unsigned int* __restrict__ aThU,
                                                     const unsigned int* __restrict__ aTlU,
                                                     const float2* __restrict__ hw,
                                                     float2* __restrict__ out1tmp,
                                                     const float4* __restrict__ p,
                                                     short4* __restrict__ aXh,
                                                     short4* __restrict__ aXl) {
    __shared__ float sARe[32 * 64];
    __shared__ float sAIm[32 * 64];
    int bid = blockIdx.x;
    int tid = threadIdx.x;
    if (bid >= 1024) {
        int f = (bid - 1024) * 256 + tid;      // 16384 float4s
        float4 s = make_float4(0.f, 0.f, 0.f, 0.f);
        for (int c = 0; c < 64; ++c) {
            float4 v = p[(size_t)c * 16384 + f];
            s.x += v.x; s.y += v.y; s.z += v.z; s.w += v.w;
        }
        short4 h, l;
        bfsplit(s.x, &h.x, &l.x);
        bfsplit(s.y, &h.y, &l.y);
        bfsplit(s.z, &h.z, &l.z);
        bfsplit(s.w, &h.w, &l.w);
        aXh[f] = h;
        aXl[f] = l;
        return;
    }
    int x = bid;
#pragma unroll
    for (int r = 0; r < 4; ++r) {
        int e = tid + (r << 8);
        int i = e >> 5, bp = e & 31;
        size_t base = ((size_t)i * T_N + x) * B_N + bp * 2;
        uint2 uh = *(const uint2*)&aThU[base];
        uint2 ul = *(const uint2*)&aTlU[base];
        float r0 = __uint_as_float(uh.x << 16) + __uint_as_float(ul.x << 16);
        float i0 = __uint_as_float(uh.x & 0xFFFF0000u) + __uint_as_float(ul.x & 0xFFFF0000u);
        float r1 = __uint_as_float(uh.y << 16) + __uint_as_float(ul.y << 16);
        float i1 = __uint_as_float(uh.y & 0xFFFF0000u) + __uint_as_float(ul.y & 0xFFFF0000u);
        *(float2*)&sARe[i * 64 + bp * 2] = make_float2(r0, r1);
        *(float2*)&sAIm[i * 64 + bp * 2] = make_float2(i0, i1);
    }
    __syncthreads();

    int o = tid & 31, bg = tid >> 5;
    const float2* hrow = hw + (size_t)x * 1024 + o;
    float accR[8] = {}, accI[8] = {};
#pragma unroll 4
    for (int i = 0; i < CIN; ++i) {
        float2 h = hrow[i * 32];
        float4 ar0 = *(const float4*)&sARe[i * 64 + bg * 8];
        float4 ar1 = *(const float4*)&sARe[i * 64 + bg * 8 + 4];
        float4 ai0 = *(const float4*)&sAIm[i * 64 + bg * 8];
        float4 ai1 = *(const float4*)&sAIm[i * 64 + bg * 8 + 4];
        float aR[8] = {ar0.x, ar0.y, ar0.z, ar0.w, ar1.x, ar1.y, ar1.z, ar1.w};
        float aI[8] = {ai0.x, ai0.y, ai0.z, ai0.w, ai1.x, ai1.y, ai1.z, ai1.w};
#pragma unroll
        for (int bb = 0; bb < 8; ++bb) {
            accR[bb] += aR[bb] * h.x - aI[bb] * h.y;
            accI[bb] += aR[bb] * h.y + aI[bb] * h.x;
        }
    }
#pragma unroll
    for (int bb = 0; bb < 8; ++bb) {
        out1tmp[(size_t)x * 2048 + (bg * 8 + bb) * 32 + o] =
            make_float2(accR[bb], accI[bb]);
    }
}

// ---------------------------------------------------------------------------
// fused: blocks [0,1024): transpose out1tmp[x][bo] -> out1T[bo][x]
//        blocks [1024,1536): x2m (stores '=' into outp; ifft adds x1 after)
// ---------------------------------------------------------------------------
__global__ __launch_bounds__(256) void k_to1_x2m(const float2* __restrict__ out1tmp,
                                                 float2* __restrict__ out1T,
                                                 const short* __restrict__ aXhS,
                                                 const short* __restrict__ aXlS,
                                                 const float* __restrict__ pr,
                                                 const float* __restrict__ pim,
                                                 float* __restrict__ outp) {
    __shared__ __align__(16) char SMEM[24576];
    int bid = blockIdx.x;
    int tid = threadIdx.x;

    if (bid < 1024) {
        float2* T = (float2*)SMEM;             // 64*33 float2 = 16896 B
        int bot = bid >> 5, xt = bid & 31;
#pragma unroll
        for (int r = 0; r < 8; ++r) {
            int e = tid + (r << 8);
            int j = e & 63, xr = e >> 6;
            T[j * 33 + xr] = out1tmp[((size_t)(xt * 32 + xr)) * 2048 + bot * 64 + j];
        }
        __syncthreads();
#pragma unroll
        for (int r = 0; r < 8; ++r) {
            int e = tid + (r << 8);
            int xx = e & 31, j = e >> 5;
            out1T[((size_t)(bot * 64 + j)) * T_N + xt * 32 + xx] = T[j * 33 + xx];
        }
        return;
    }

    short* sAh = (short*)SMEM;
    short* sAl = sAh + 64 * ABROW;
    short* sBh = sAl + 64 * ABROW;
    short* sBl = sBh + 64 * ABROW;
    float* s_pr = (float*)(SMEM + 20480);
    float* s_pim = s_pr + 512;

    int zz = bid - 1024;
    const int zb = zz & 15, o = zz >> 4;
    const int w = tid >> 6, l = tid & 63;
    const int r = l & 15, hg = l >> 4;

#pragma unroll
    for (int rr_ = 0; rr_ < 2; ++rr_) {
        int cm = tid + (rr_ << 8);
        int c = cm >> 4, m = cm & 15;
        int pidx = (c * COUT + o) * MODES + m;
        s_pr[cm] = pr[pidx];
        s_pim[cm] = pim[pidx];
    }
    __syncthreads();

    f32x4 acc0 = {0.f, 0.f, 0.f, 0.f};
    f32x4 acc1 = {0.f, 0.f, 0.f, 0.f};
    f32x4 acc2 = {0.f, 0.f, 0.f, 0.f};
    f32x4 acc3 = {0.f, 0.f, 0.f, 0.f};

    const int sb = tid >> 2;
    const int sc = (tid & 3) * 8;
    const float z0f = (float)(zb * 64);

    const int bz = tid & 63, bh = tid >> 6;
    const float tz = (z0f + (float)bz) * DT;

    for (int ks = 0; ks < 32; ++ks) {
        __syncthreads();
        *(float4*)&sAh[sb * ABROW + sc] = *(const float4*)&aXhS[sb * 1024 + ks * 32 + sc];
        *(float4*)&sAl[sb * ABROW + sc] = *(const float4*)&aXlS[sb * 1024 + ks * 32 + sc];
        {
            bf16x8 vh, vl;
#pragma unroll
            for (int j4 = 0; j4 < 4; ++j4) {
                int cml = bh * 4 + j4;
                int cm = ks * 16 + cml;
                float gr = s_pr[cm], gi = s_pim[cm];
                float er = __expf(gr * tz);
                float sn, cn;
                __sincosf(gi * tz, &sn, &cn);
                short h1, l1, h2, l2;
                bfsplit(er * cn,  &h1, &l1);
                bfsplit(-er * sn, &h2, &l2);
                vh[j4 * 2] = h1; vh[j4 * 2 + 1] = h2;
                vl[j4 * 2] = l1; vl[j4 * 2 + 1] = l2;
            }
            *(bf16x8*)&sBh[bz * ABROW + bh * 8] = vh;
            *(bf16x8*)&sBl[bz * ABROW + bh * 8] = vl;
        }
        __syncthreads();

        bf16x8 bhf = *(bf16x8*)&sBh[(w * 16 + r) * ABROW + hg * 8];
        bf16x8 blf = *(bf16x8*)&sBl[(w * 16 + r) * ABROW + hg * 8];
        {
            bf16x8 ah = *(bf16x8*)&sAh[(0 * 16 + r) * ABROW + hg * 8];
            bf16x8 al = *(bf16x8*)&sAl[(0 * 16 + r) * ABROW + hg * 8];
            acc0 = __builtin_amdgcn_mfma_f32_16x16x32_bf16(ah, bhf, acc0, 0, 0, 0);
            acc0 = __builtin_amdgcn_mfma_f32_16x16x32_bf16(al, bhf, acc0, 0, 0, 0);
            acc0 = __builtin_amdgcn_mfma_f32_16x16x32_bf16(ah, blf, acc0, 0, 0, 0);
        }
        {
            bf16x8 ah = *(bf16x8*)&sAh[(1 * 16 + r) * ABROW + hg * 8];
            bf16x8 al = *(bf16x8*)&sAl[(1 * 16 + r) * ABROW + hg * 8];
            acc1 = __builtin_amdgcn_mfma_f32_16x16x32_bf16(ah, bhf, acc1, 0, 0, 0);
            acc1 = __builtin_amdgcn_mfma_f32_16x16x32_bf16(al, bhf, acc1, 0, 0, 0);
            acc1 = __builtin_amdgcn_mfma_f32_16x16x32_bf16(ah, blf, acc1, 0, 0, 0);
        }
        {
            bf16x8 ah = *(bf16x8*)&sAh[(2 * 16 + r) * ABROW + hg * 8];
            bf16x8 al = *(bf16x8*)&sAl[(2 * 16 + r) * ABROW + hg * 8];
            acc2 = __builtin_amdgcn_mfma_f32_16x16x32_bf16(ah, bhf, acc2, 0, 0, 0);
            acc2 = __builtin_amdgcn_mfma_f32_16x16x32_bf16(al, bhf, acc2, 0, 0, 0);
            acc2 = __builtin_amdgcn_mfma_f32_16x16x32_bf16(ah, blf, acc2, 0, 0, 0);
        }
        {
            bf16x8 ah = *(bf16x8*)&sAh[(3 * 16 + r) * ABROW + hg * 8];
            bf16x8 al = *(bf16x8*)&sAl[(3 * 16 + r) * ABROW + hg * 8];
            acc3 = __builtin_amdgcn_mfma_f32_16x16x32_bf16(ah, bhf, acc3, 0, 0, 0);
            acc3 = __builtin_amdgcn_mfma_f32_16x16x32_bf16(al, bhf, acc3, 0, 0, 0);
            acc3 = __builtin_amdgcn_mfma_f32_16x16x32_bf16(ah, blf, acc3, 0, 0, 0);
        }
    }

    const float inv_n = 1.0f / (float)T_N;
    size_t base = (size_t)o * T_N + zb * 64 + w * 16 + r;
#pragma unroll
    for (int reg = 0; reg < 4; ++reg) {
        size_t i0 = base + (size_t)(0 * 16 + hg * 4 + reg) * (COUT * T_N);
        size_t i1 = base + (size_t)(1 * 16 + hg * 4 + reg) * (COUT * T_N);
        size_t i2 = base + (size_t)(2 * 16 + hg * 4 + reg) * (COUT * T_N);
        size_t i3 = base + (size_t)(3 * 16 + hg * 4 + reg) * (COUT * T_N);
        outp[i0] = acc0[reg] * inv_n;   // store '='; ifft adds x1 after
        outp[i1] = acc1[reg] * inv_n;
        outp[i2] = acc2[reg] * inv_n;
        outp[i3] = acc3[reg] * inv_n;
    }
}

// ---------------------------------------------------------------------------
// ifft: x1 added on top of x2 (outp already holds x2 contribution).
// ---------------------------------------------------------------------------
__global__ __launch_bounds__(256) void k_ifft(const float2* __restrict__ out1T,
                                              float* __restrict__ outp) {
    __shared__ float2 A[1024];
    __shared__ float2 Bb[1024];
    __shared__ float2 TW[1024];
    int row = blockIdx.x;
    int tid = threadIdx.x;
    build_tw4<1>(TW, tid);
    const float2* src = out1T + (size_t)row * T_N;
#pragma unroll
    for (int r = 0; r < 4; ++r) {
        int j = tid + (r << 8);
        A[j] = src[j];
    }
    float2* R = fft1024_r4<1>(A, Bb, TW, tid);
    float* dst = outp + (size_t)row * T_N;
    const float inv_n = 1.0f / (float)T_N;
#pragma unroll
    for (int r = 0; r < 4; ++r) {
        int j = tid + (r << 8);
        dst[j] += R[j].x * inv_n;
    }
}

// ---------------------------------------------------------------------------
// Layout (ws >= 65MB, proven by R9/R10's active 65MB tier):
//   [0,16M):  alpha -> o2part
//   [16,24M): aThU ; [24,32M): aTlU ; [16,32M) reused as out1T
//   [32M,+):  aXh, aXl, pol4
//   [33,37):  aHi ; [37,41): aLo
//   [41,49):  hw
//   [49,65):  out1tmp
// ---------------------------------------------------------------------------
extern "C" void kernel_launch(void* const* d_in, const int* in_sizes, int n_in,
                              void* d_out, int out_size, void* d_ws, size_t ws_size,
                              hipStream_t stream) {
    const float* x   = (const float*)d_in[0];
    const float* pr  = (const float*)d_in[2];
    const float* pim = (const float*)d_in[3];
    const float* rr  = (const float*)d_in[4];
    const float* ri  = (const float*)d_in[5];
    float* outp = (float*)d_out;

    char* ws = (char*)d_ws;
    const size_t MB = 1024 * 1024;
    const size_t KB = 1024;
    float2*       alpha  = (float2*)ws;                        // [0,16M)
    unsigned int* aThU   = (unsigned int*)(ws + 16 * MB);      // [16,24)
    unsigned int* aTlU   = (unsigned int*)(ws + 24 * MB);      // [24,32)
    short*        aXh    = (short*)(ws + 32 * MB);             // 128K
    short*        aXl    = (short*)(ws + 32 * MB + 128 * KB);  // 128K
    float4*       pol4   = (float4*)(ws + 32 * MB + 512 * KB); // 256K
    short*        aHi    = (short*)(ws + 33 * MB);             // [33,37)
    short*        aLo    = (short*)(ws + 37 * MB);             // [37,41)
    float2*       hw     = (float2*)(ws + 41 * MB);            // [41,49)
    float2*       out1tmp = (float2*)(ws + 49 * MB);           // [49,65)
    float*        o2part  = (float*)ws;                        // alpha dead
    float2*       out1T   = (float2*)(ws + 16 * MB);           // aT dead

    k_fft_fwd     <<<B_N * CIN, 256, 0, stream>>>(x, alpha, aHi, aLo,
                                                  pr, pim, rr, ri, pol4);
    k_thw_out2m   <<<2304, 256, 0, stream>>>(alpha, aThU, aTlU, pol4, hw,
                                             aHi, aLo, pr, pim, rr, ri, o2part);
    k_out1_reduce <<<1088, 256, 0, stream>>>(aThU, aTlU, hw, out1tmp,
                                             (const float4*)o2part,
                                             (short4*)aXh, (short4*)aXl);
    k_to1_x2m     <<<1536, 256, 0, stream>>>(out1tmp, out1T, aXh, aXl,
                                             pr, pim, outp);
    k_ifft        <<<B_N * COUT, 256, 0, stream>>>(out1T, outp);
}

// Round 22
// 112.573 us; speedup vs baseline: 1.2629x; 1.2629x over previous
//
#include <hip/hip_runtime.h>

#define T_N   1024
#define B_N   64
#define CIN   32
#define COUT  32
#define MODES 16
#define DT    0.01f
#define PI_F  3.14159265358979323846f
#define W_SCALE 0.613592315154256f   /* 2*pi/(T_N*DT) */
#define W_NYQ  (-314.1592653589793f) /* -pi/DT */

typedef short bf16x8 __attribute__((ext_vector_type(8)));
typedef float f32x4 __attribute__((ext_vector_type(4)));

__device__ __forceinline__ float fastrcp(float x) {
    float r;
    asm("v_rcp_f32 %0, %1" : "=v"(r) : "v"(x));
    return r;
}

// cheap split: truncate hi, truncate lo (pair error <= 2^-16 rel)
__device__ __forceinline__ void bfsplit(float v, short* ph, short* pl) {
    unsigned int u = __float_as_uint(v);
    float lo = v - __uint_as_float(u & 0xFFFF0000u);
    *ph = (short)(u >> 16);
    *pl = (short)(__float_as_uint(lo) >> 16);
}

// ---------------------------------------------------------------------------
// Radix-4 Stockham FFT, length 1024, 5 stages, LDS twiddle table (1024 ent).
// ---------------------------------------------------------------------------
template <int SIGN>
__device__ __forceinline__ float2* fft1024_r4(float2* A, float2* B,
                                              const float2* TW, int tid) {
    float2* src = A;
    float2* dst = B;
    int m = 1;
#pragma unroll
    for (int s = 0; s < 5; ++s) {
        __syncthreads();
        int k  = tid & (m - 1);
        int jm = tid - k;                       // j*m
        float2 a = src[tid];
        float2 b = src[tid + 256];
        float2 c = src[tid + 512];
        float2 d = src[tid + 768];
        float2 t0 = make_float2(a.x + c.x, a.y + c.y);
        float2 t1 = make_float2(a.x - c.x, a.y - c.y);
        float2 t2 = make_float2(b.x + d.x, b.y + d.y);
        float2 t3 = make_float2(b.x - d.x, b.y - d.y);
        float2 it3 = (SIGN == 1) ? make_float2(-t3.y, t3.x)
                                 : make_float2(t3.y, -t3.x);
        float2 y0 = make_float2(t0.x + t2.x, t0.y + t2.y);
        float2 y2 = make_float2(t0.x - t2.x, t0.y - t2.y);
        float2 y1 = make_float2(t1.x + it3.x, t1.y + it3.y);
        float2 y3 = make_float2(t1.x - it3.x, t1.y - it3.y);
        float2 w1 = TW[jm];
        float2 w2 = TW[2 * jm];
        float2 w3 = TW[3 * jm];
        int ob = k + 4 * jm;
        dst[ob] = y0;
        dst[ob + m]     = make_float2(w1.x * y1.x - w1.y * y1.y,
                                      w1.x * y1.y + w1.y * y1.x);
        dst[ob + 2 * m] = make_float2(w2.x * y2.x - w2.y * y2.y,
                                      w2.x * y2.y + w2.y * y2.x);
        dst[ob + 3 * m] = make_float2(w3.x * y3.x - w3.y * y3.y,
                                      w3.x * y3.y + w3.y * y3.x);
        float2* t = src; src = dst; dst = t;
        m <<= 2;
    }
    __syncthreads();
    return src;
}

template <int SIGN>
__device__ __forceinline__ void build_tw4(float2* TW, int tid) {
#pragma unroll
    for (int r = 0; r < 4; ++r) {
        int a = tid + (r << 8);                 // 0..1023
        float sn, cs;
        __sincosf((float)SIGN * PI_F * (float)a * (1.0f / 512.0f), &sn, &cs);
        TW[a] = make_float2(cs, sn);
    }
}

// ---------------------------------------------------------------------------
// forward FFT + fused split-bf16 conversion + (blocks 0-63) pol4 pack.
// ---------------------------------------------------------------------------
__global__ __launch_bounds__(256) void k_fft_fwd(const float* __restrict__ x,
                                                 float2* __restrict__ alpha,
                                                 short* __restrict__ aHi,
                                                 short* __restrict__ aLo,
                                                 const float* __restrict__ pr,
                                                 const float* __restrict__ pim,
                                                 const float* __restrict__ rr,
                                                 const float* __restrict__ ri,
                                                 float4* __restrict__ pol4) {
    __shared__ float2 A[1024];
    __shared__ float2 Bb[1024];
    __shared__ float2 TW[1024];
    int row = blockIdx.x;
    int tid = threadIdx.x;
    build_tw4<-1>(TW, tid);
    const float* xr = x + (size_t)row * T_N;
#pragma unroll
    for (int r = 0; r < 4; ++r) {
        int j = tid + (r << 8);
        A[j] = make_float2(xr[j], 0.0f);
    }
    float2* R = fft1024_r4<-1>(A, Bb, TW, tid);
    float2* outp = alpha + (size_t)row * T_N;
#pragma unroll
    for (int r = 0; r < 4; ++r) {
        int j = tid + (r << 8);
        outp[j] = R[j];
    }
    size_t base = (size_t)row * 1024;
#pragma unroll
    for (int rr_ = 0; rr_ < 2; ++rr_) {
        int xj = tid + (rr_ << 8);        // 0..511
        float2 v = R[xj];
        float aR = v.x;
        float aI = (xj == 0) ? R[512].x : v.y;
        short h0, l0, h1, l1;
        bfsplit(aR, &h0, &l0);
        bfsplit(aI, &h1, &l1);
        aHi[base + xj * 2]     = h0;
        aHi[base + xj * 2 + 1] = h1;
        aLo[base + xj * 2]     = l0;
        aLo[base + xj * 2 + 1] = l1;
    }
    if (row < 64) {
        int idx = row * 256 + tid;
        pol4[idx] = make_float4(pr[idx], pim[idx], rr[idx], ri[idx]);
    }
}

// ---------------------------------------------------------------------------
// fused triple kernel (register-balanced):
//   blocks [0,1024):     transpose alpha -> packed bf16 aT[i][x][b]
//   blocks [1024,1280):  Hw table (STREAMING pol4 reads, low-VGPR)
//   blocks [1280,2304):  out2 MFMA -> partial[chunk=(i*2+xh)][b][n]
// LDS overlay: max(16.9KB transpose, 21.0KB out2m) = 21.0KB.
// ---------------------------------------------------------------------------
#define ABROW 40   /* shorts per LDS row: 32 data + 8 pad (80B) */
__global__ __launch_bounds__(256) void k_thw_out2m(const float2* __restrict__ alpha,
                                                   unsigned int* __restrict__ aThU,
                                                   unsigned int* __restrict__ aTlU,
                                                   const float4* __restrict__ pol4,
                                                   float2* __restrict__ hw,
                                                   const short* __restrict__ aHi,
                                                   const short* __restrict__ aLo,
                                                   const float* __restrict__ pr,
                                                   const float* __restrict__ pim,
                                                   const float* __restrict__ rr,
                                                   const float* __restrict__ ri,
                                                   float* __restrict__ partial) {
    __shared__ __align__(16) char SMEM[20992];
    int bid = blockIdx.x;
    int tid = threadIdx.x;

    if (bid < 1024) {
        // ---- transpose path ----
        float2* T = (float2*)SMEM;             // 32*66 float2 = 16896 B
        int i = bid >> 5, xt = bid & 31;
#pragma unroll
        for (int r = 0; r < 8; ++r) {
            int e = tid + (r << 8);
            int xx = e & 31, b = e >> 5;
            T[xx * 66 + b] = alpha[((size_t)(b * CIN + i)) * T_N + xt * 32 + xx];
        }
        __syncthreads();
#pragma unroll
        for (int r = 0; r < 8; ++r) {
            int e = tid + (r << 8);
            int b = e & 63, xx = e >> 6;
            float2 v = T[xx * 66 + b];
            short hR, lR, hI, lI;
            bfsplit(v.x, &hR, &lR);
            bfsplit(v.y, &hI, &lI);
            size_t idx = ((size_t)i * T_N + xt * 32 + xx) * B_N + b;
            aThU[idx] = (unsigned int)(unsigned short)hR |
                        ((unsigned int)(unsigned short)hI << 16);
            aTlU[idx] = (unsigned int)(unsigned short)lR |
                        ((unsigned int)(unsigned short)lI << 16);
        }
        return;
    }
    if (bid < 1280) {
        // ---- Hw path: streaming pol4 (low register footprint) ----
        int xb = bid - 1024;
        int io0 = tid * 4;
        float wv[4];
#pragma unroll
        for (int xi = 0; xi < 4; ++xi) {
            int xg = xb * 4 + xi;
            int fx = xg - ((xg >= 512) ? 1024 : 0);
            wv[xi] = (float)fx * W_SCALE;
        }
        float accR[4][4] = {}, accI[4][4] = {};   // [xi][j]
#pragma unroll
        for (int j = 0; j < 4; ++j) {
            const float4* pp = pol4 + (io0 + j) * 16;
#pragma unroll 1
            for (int k = 0; k < 16; ++k) {
                float4 p = pp[k];
#pragma unroll
                for (int xi = 0; xi < 4; ++xi) {
                    float d = wv[xi] - p.y;
                    float inv = fastrcp(fmaf(d, d, p.x * p.x));
                    float vR = -p.x * inv, vI = -d * inv;
                    accR[xi][j] += p.z * vR - p.w * vI;
                    accI[xi][j] += p.z * vI + p.w * vR;
                }
            }
        }
#pragma unroll
        for (int xi = 0; xi < 4; ++xi) {
            float4* dst = (float4*)(hw + (size_t)(xb * 4 + xi) * 1024 + io0);
            dst[0] = make_float4(accR[xi][0], accI[xi][0], accR[xi][1], accI[xi][1]);
            dst[1] = make_float4(accR[xi][2], accI[xi][2], accR[xi][3], accI[xi][3]);
        }
        return;
    }

    // ---- out2 MFMA path ----
    short* sAh = (short*)SMEM;                 // 2560 shorts each
    short* sAl = sAh + 64 * ABROW;
    short* sBh = sAl + 64 * ABROW;
    short* sBl = sBh + 64 * ABROW;             // ends at 20480 B
    float* sPol = (float*)(SMEM + 20480);      // 4*32 floats -> 20992 B

    int idx2 = bid - 1280;                     // 0..1023
    const int nb = idx2 & 15, xh = (idx2 >> 4) & 1, i = idx2 >> 5;
    const int w = tid >> 6, l = tid & 63;
    const int r = l & 15, hg = l >> 4;

    if (tid < 32) {
        int o = nb * 2 + (tid >> 4), k = tid & 15;
        int pidx = (i * COUT + o) * MODES + k;
        sPol[0 * 32 + tid] = pr[pidx]; sPol[1 * 32 + tid] = pim[pidx];
        sPol[2 * 32 + tid] = rr[pidx]; sPol[3 * 32 + tid] = ri[pidx];
    }
    __syncthreads();

    f32x4 acc0 = {0.f, 0.f, 0.f, 0.f};
    f32x4 acc1 = {0.f, 0.f, 0.f, 0.f};
    f32x4 acc2 = {0.f, 0.f, 0.f, 0.f};
    f32x4 acc3 = {0.f, 0.f, 0.f, 0.f};

    const int sb = tid >> 2;
    const int sc = (tid & 3) * 8;
    const size_t abase = ((size_t)sb * CIN + i) * 1024 + (size_t)xh * 512;

    const int bn = tid & 63, bh = tid >> 6;
    const int bok = bn >> 1, bcomp = bn & 1;
    const float pa = sPol[0 * 32 + bok], pb = sPol[1 * 32 + bok];
    const float prr_ = sPol[2 * 32 + bok], pri_ = sPol[3 * 32 + bok];
    const float K_d  = pa * pa - pb * pb;
    const float mKe  = -2.0f * pa * pb;
    const float K_e2 = (2.0f * pa * pb) * (2.0f * pa * pb);
    const float prx2 = 2.0f * (pa * prr_ - pb * pri_);
    const float piy2 = 2.0f * (pa * pri_ + pb * prr_);
    const float A1 = bcomp ? piy2 : prx2;
    const float B1 = bcomp ? prx2 : -piy2;
    const float A2 = bcomp ? pri_ : prr_;
    const float B2 = bcomp ? prr_ : -pri_;

    for (int ks = 0; ks < 16; ++ks) {
        __syncthreads();
        *(float4*)&sAh[sb * ABROW + sc] = *(const float4*)&aHi[abase + ks * 32 + sc];
        *(float4*)&sAl[sb * ABROW + sc] = *(const float4*)&aLo[abase + ks * 32 + sc];
        {
            bf16x8 vh, vl;
#pragma unroll
            for (int j4 = 0; j4 < 4; ++j4) {
                int xl = bh * 4 + j4;
                int xg = xh * 256 + ks * 16 + xl;
                float v1, v2;
                if (xg == 0) {
                    float s1 = pa * pa + pb * pb;
                    float q1r = pa / s1, q1i = -pb / s1;
                    float c1r = prr_ * q1r - pri_ * q1i;
                    float c1i = prr_ * q1i + pri_ * q1r;
                    float dr = -pa, di = W_NYQ - pb;
                    float s2 = dr * dr + di * di;
                    float q2r = dr / s2, q2i = -di / s2;
                    float c2r = -(prr_ * q2r - pri_ * q2i);
                    float c2i = -(prr_ * q2i + pri_ * q2r);
                    v1 = bcomp ? c1i : c1r;
                    v2 = bcomp ? c2i : c2r;
                } else {
                    float wv = (float)xg * W_SCALE;
                    float denr = fmaf(wv, wv, K_d);
                    float s = fmaf(denr, denr, K_e2);
                    float inv = fastrcp(s);
                    float qr = denr * inv, qi = mKe * inv;
                    v1 = A1 * qr + B1 * qi;
                    float rq = A2 * qr + B2 * qi;
                    v2 = -2.0f * wv * rq;
                }
                short h1, l1, h2, l2;
                bfsplit(v1, &h1, &l1);
                bfsplit(v2, &h2, &l2);
                vh[j4 * 2] = h1; vh[j4 * 2 + 1] = h2;
                vl[j4 * 2] = l1; vl[j4 * 2 + 1] = l2;
            }
            *(bf16x8*)&sBh[bn * ABROW + bh * 8] = vh;
            *(bf16x8*)&sBl[bn * ABROW + bh * 8] = vl;
        }
        __syncthreads();

        bf16x8 bhf = *(bf16x8*)&sBh[(w * 16 + r) * ABROW + hg * 8];
        bf16x8 blf = *(bf16x8*)&sBl[(w * 16 + r) * ABROW + hg * 8];
        {
            bf16x8 ah = *(bf16x8*)&sAh[(0 * 16 + r) * ABROW + hg * 8];
            bf16x8 al = *(bf16x8*)&sAl[(0 * 16 + r) * ABROW + hg * 8];
            acc0 = __builtin_amdgcn_mfma_f32_16x16x32_bf16(ah, bhf, acc0, 0, 0, 0);
            acc0 = __builtin_amdgcn_mfma_f32_16x16x32_bf16(al, bhf, acc0, 0, 0, 0);
            acc0 = __builtin_amdgcn_mfma_f32_16x16x32_bf16(ah, blf, acc0, 0, 0, 0);
        }
        {
            bf16x8 ah = *(bf16x8*)&sAh[(1 * 16 + r) * ABROW + hg * 8];
            bf16x8 al = *(bf16x8*)&sAl[(1 * 16 + r) * ABROW + hg * 8];
            acc1 = __builtin_amdgcn_mfma_f32_16x16x32_bf16(ah, bhf, acc1, 0, 0, 0);
            acc1 = __builtin_amdgcn_mfma_f32_16x16x32_bf16(al, bhf, acc1, 0, 0, 0);
            acc1 = __builtin_amdgcn_mfma_f32_16x16x32_bf16(ah, blf, acc1, 0, 0, 0);
        }
        {
            bf16x8 ah = *(bf16x8*)&sAh[(2 * 16 + r) * ABROW + hg * 8];
            bf16x8 al = *(bf16x8*)&sAl[(2 * 16 + r) * ABROW + hg * 8];
            acc2 = __builtin_amdgcn_mfma_f32_16x16x32_bf16(ah, bhf, acc2, 0, 0, 0);
            acc2 = __builtin_amdgcn_mfma_f32_16x16x32_bf16(al, bhf, acc2, 0, 0, 0);
            acc2 = __builtin_amdgcn_mfma_f32_16x16x32_bf16(ah, blf, acc2, 0, 0, 0);
        }
        {
            bf16x8 ah = *(bf16x8*)&sAh[(3 * 16 + r) * ABROW + hg * 8];
            bf16x8 al = *(bf16x8*)&sAl[(3 * 16 + r) * ABROW + hg * 8];
            acc3 = __builtin_amdgcn_mfma_f32_16x16x32_bf16(ah, bhf, acc3, 0, 0, 0);
            acc3 = __builtin_amdgcn_mfma_f32_16x16x32_bf16(al, bhf, acc3, 0, 0, 0);
            acc3 = __builtin_amdgcn_mfma_f32_16x16x32_bf16(ah, blf, acc3, 0, 0, 0);
        }
    }

    int chunk = i * 2 + xh;
    int n = nb * 64 + w * 16 + r;
    float* dst = partial + (size_t)chunk * (B_N * 1024) + n;
#pragma unroll
    for (int reg = 0; reg < 4; ++reg) {
        dst[(0 * 16 + hg * 4 + reg) * 1024] = acc0[reg];
        dst[(1 * 16 + hg * 4 + reg) * 1024] = acc1[reg];
        dst[(2 * 16 + hg * 4 + reg) * 1024] = acc2[reg];
        dst[(3 * 16 + hg * 4 + reg) * 1024] = acc3[reg];
    }
}

// ---------------------------------------------------------------------------
// fused: blocks [0,1024): out1 (alpha-slice MAC vs hw row)
//        blocks [1024,1088): reduce 64 partials -> split-bf16 aXh/aXl
// ---------------------------------------------------------------------------
__global__ __launch_bounds__(256) void k_out1_reduce(const unsigned int* __restrict__ aThU,
                                                     const unsigned int* __restrict__ aTlU,
                                                     const float2* __restrict__ hw,
                                                     float2* __restrict__ out1tmp,
                                                     const float4* __restrict__ p,
                                                     short4* __restrict__ aXh,
                                                     short4* __restrict__ aXl) {
    __shared__ float sARe[32 * 64];
    __shared__ float sAIm[32 * 64];
    int bid = blockIdx.x;
    int tid = threadIdx.x;
    if (bid >= 1024) {
        int f = (bid - 1024) * 256 + tid;      // 16384 float4s
        float4 s = make_float4(0.f, 0.f, 0.f, 0.f);
        for (int c = 0; c < 64; ++c) {
            float4 v = p[(size_t)c * 16384 + f];
            s.x += v.x; s.y += v.y; s.z += v.z; s.w += v.w;
        }
        short4 h, l;
        bfsplit(s.x, &h.x, &l.x);
        bfsplit(s.y, &h.y, &l.y);
        bfsplit(s.z, &h.z, &l.z);
        bfsplit(s.w, &h.w, &l.w);
        aXh[f] = h;
        aXl[f] = l;
        return;
    }
    int x = bid;
#pragma unroll
    for (int r = 0; r < 4; ++r) {
        int e = tid + (r << 8);
        int i = e >> 5, bp = e & 31;
        size_t base = ((size_t)i * T_N + x) * B_N + bp * 2;
        uint2 uh = *(const uint2*)&aThU[base];
        uint2 ul = *(const uint2*)&aTlU[base];
        float r0 = __uint_as_float(uh.x << 16) + __uint_as_float(ul.x << 16);
        float i0 = __uint_as_float(uh.x & 0xFFFF0000u) + __uint_as_float(ul.x & 0xFFFF0000u);
        float r1 = __uint_as_float(uh.y << 16) + __uint_as_float(ul.y << 16);
        float i1 = __uint_as_float(uh.y & 0xFFFF0000u) + __uint_as_float(ul.y & 0xFFFF0000u);
        *(float2*)&sARe[i * 64 + bp * 2] = make_float2(r0, r1);
        *(float2*)&sAIm[i * 64 + bp * 2] = make_float2(i0, i1);
    }
    __syncthreads();

    int o = tid & 31, bg = tid >> 5;
    const float2* hrow = hw + (size_t)x * 1024 + o;
    float accR[8] = {}, accI[8] = {};
#pragma unroll 4
    for (int i = 0; i < CIN; ++i) {
        float2 h = hrow[i * 32];
        float4 ar0 = *(const float4*)&sARe[i * 64 + bg * 8];
        float4 ar1 = *(const float4*)&sARe[i * 64 + bg * 8 + 4];
        float4 ai0 = *(const float4*)&sAIm[i * 64 + bg * 8];
        float4 ai1 = *(const float4*)&sAIm[i * 64 + bg * 8 + 4];
        float aR[8] = {ar0.x, ar0.y, ar0.z, ar0.w, ar1.x, ar1.y, ar1.z, ar1.w};
        float aI[8] = {ai0.x, ai0.y, ai0.z, ai0.w, ai1.x, ai1.y, ai1.z, ai1.w};
#pragma unroll
        for (int bb = 0; bb < 8; ++bb) {
            accR[bb] += aR[bb] * h.x - aI[bb] * h.y;
            accI[bb] += aR[bb] * h.y + aI[bb] * h.x;
        }
    }
#pragma unroll
    for (int bb = 0; bb < 8; ++bb) {
        out1tmp[(size_t)x * 2048 + (bg * 8 + bb) * 32 + o] =
            make_float2(accR[bb], accI[bb]);
    }
}

// ---------------------------------------------------------------------------
// fused: blocks [0,1024): transpose out1tmp[x][bo] -> out1T[bo][x]
//        blocks [1024,1536): x2m (stores '=' into outp; ifft adds x1 after)
// ---------------------------------------------------------------------------
__global__ __launch_bounds__(256) void k_to1_x2m(const float2* __restrict__ out1tmp,
                                                 float2* __restrict__ out1T,
                                                 const short* __restrict__ aXhS,
                                                 const short* __restrict__ aXlS,
                                                 const float* __restrict__ pr,
                                                 const float* __restrict__ pim,
                                                 float* __restrict__ outp) {
    __shared__ __align__(16) char SMEM[24576];
    int bid = blockIdx.x;
    int tid = threadIdx.x;

    if (bid < 1024) {
        float2* T = (float2*)SMEM;             // 64*33 float2 = 16896 B
        int bot = bid >> 5, xt = bid & 31;
#pragma unroll
        for (int r = 0; r < 8; ++r) {
            int e = tid + (r << 8);
            int j = e & 63, xr = e >> 6;
            T[j * 33 + xr] = out1tmp[((size_t)(xt * 32 + xr)) * 2048 + bot * 64 + j];
        }
        __syncthreads();
#pragma unroll
        for (int r = 0; r < 8; ++r) {
            int e = tid + (r << 8);
            int xx = e & 31, j = e >> 5;
            out1T[((size_t)(bot * 64 + j)) * T_N + xt * 32 + xx] = T[j * 33 + xx];
        }
        return;
    }

    short* sAh = (short*)SMEM;
    short* sAl = sAh + 64 * ABROW;
    short* sBh = sAl + 64 * ABROW;
    short* sBl = sBh + 64 * ABROW;
    float* s_pr = (float*)(SMEM + 20480);
    float* s_pim = s_pr + 512;

    int zz = bid - 1024;
    const int zb = zz & 15, o = zz >> 4;
    const int w = tid >> 6, l = tid & 63;
    const int r = l & 15, hg = l >> 4;

#pragma unroll
    for (int rr_ = 0; rr_ < 2; ++rr_) {
        int cm = tid + (rr_ << 8);
        int c = cm >> 4, m = cm & 15;
        int pidx = (c * COUT + o) * MODES + m;
        s_pr[cm] = pr[pidx];
        s_pim[cm] = pim[pidx];
    }
    __syncthreads();

    f32x4 acc0 = {0.f, 0.f, 0.f, 0.f};
    f32x4 acc1 = {0.f, 0.f, 0.f, 0.f};
    f32x4 acc2 = {0.f, 0.f, 0.f, 0.f};
    f32x4 acc3 = {0.f, 0.f, 0.f, 0.f};

    const int sb = tid >> 2;
    const int sc = (tid & 3) * 8;
    const float z0f = (float)(zb * 64);

    const int bz = tid & 63, bh = tid >> 6;
    const float tz = (z0f + (float)bz) * DT;

    for (int ks = 0; ks < 32; ++ks) {
        __syncthreads();
        *(float4*)&sAh[sb * ABROW + sc] = *(const float4*)&aXhS[sb * 1024 + ks * 32 + sc];
        *(float4*)&sAl[sb * ABROW + sc] = *(const float4*)&aXlS[sb * 1024 + ks * 32 + sc];
        {
            bf16x8 vh, vl;
#pragma unroll
            for (int j4 = 0; j4 < 4; ++j4) {
                int cml = bh * 4 + j4;
                int cm = ks * 16 + cml;
                float gr = s_pr[cm], gi = s_pim[cm];
                float er = __expf(gr * tz);
                float sn, cn;
                __sincosf(gi * tz, &sn, &cn);
                short h1, l1, h2, l2;
                bfsplit(er * cn,  &h1, &l1);
                bfsplit(-er * sn, &h2, &l2);
                vh[j4 * 2] = h1; vh[j4 * 2 + 1] = h2;
                vl[j4 * 2] = l1; vl[j4 * 2 + 1] = l2;
            }
            *(bf16x8*)&sBh[bz * ABROW + bh * 8] = vh;
            *(bf16x8*)&sBl[bz * ABROW + bh * 8] = vl;
        }
        __syncthreads();

        bf16x8 bhf = *(bf16x8*)&sBh[(w * 16 + r) * ABROW + hg * 8];
        bf16x8 blf = *(bf16x8*)&sBl[(w * 16 + r) * ABROW + hg * 8];
        {
            bf16x8 ah = *(bf16x8*)&sAh[(0 * 16 + r) * ABROW + hg * 8];
            bf16x8 al = *(bf16x8*)&sAl[(0 * 16 + r) * ABROW + hg * 8];
            acc0 = __builtin_amdgcn_mfma_f32_16x16x32_bf16(ah, bhf, acc0, 0, 0, 0);
            acc0 = __builtin_amdgcn_mfma_f32_16x16x32_bf16(al, bhf, acc0, 0, 0, 0);
            acc0 = __builtin_amdgcn_mfma_f32_16x16x32_bf16(ah, blf, acc0, 0, 0, 0);
        }
        {
            bf16x8 ah = *(bf16x8*)&sAh[(1 * 16 + r) * ABROW + hg * 8];
            bf16x8 al = *(bf16x8*)&sAl[(1 * 16 + r) * ABROW + hg * 8];
            acc1 = __builtin_amdgcn_mfma_f32_16x16x32_bf16(ah, bhf, acc1, 0, 0, 0);
            acc1 = __builtin_amdgcn_mfma_f32_16x16x32_bf16(al, bhf, acc1, 0, 0, 0);
            acc1 = __builtin_amdgcn_mfma_f32_16x16x32_bf16(ah, blf, acc1, 0, 0, 0);
        }
        {
            bf16x8 ah = *(bf16x8*)&sAh[(2 * 16 + r) * ABROW + hg * 8];
            bf16x8 al = *(bf16x8*)&sAl[(2 * 16 + r) * ABROW + hg * 8];
            acc2 = __builtin_amdgcn_mfma_f32_16x16x32_bf16(ah, bhf, acc2, 0, 0, 0);
            acc2 = __builtin_amdgcn_mfma_f32_16x16x32_bf16(al, bhf, acc2, 0, 0, 0);
            acc2 = __builtin_amdgcn_mfma_f32_16x16x32_bf16(ah, blf, acc2, 0, 0, 0);
        }
        {
            bf16x8 ah = *(bf16x8*)&sAh[(3 * 16 + r) * ABROW + hg * 8];
            bf16x8 al = *(bf16x8*)&sAl[(3 * 16 + r) * ABROW + hg * 8];
            acc3 = __builtin_amdgcn_mfma_f32_16x16x32_bf16(ah, bhf, acc3, 0, 0, 0);
            acc3 = __builtin_amdgcn_mfma_f32_16x16x32_bf16(al, bhf, acc3, 0, 0, 0);
            acc3 = __builtin_amdgcn_mfma_f32_16x16x32_bf16(ah, blf, acc3, 0, 0, 0);
        }
    }

    const float inv_n = 1.0f / (float)T_N;
    size_t base = (size_t)o * T_N + zb * 64 + w * 16 + r;
#pragma unroll
    for (int reg = 0; reg < 4; ++reg) {
        size_t i0 = base + (size_t)(0 * 16 + hg * 4 + reg) * (COUT * T_N);
        size_t i1 = base + (size_t)(1 * 16 + hg * 4 + reg) * (COUT * T_N);
        size_t i2 = base + (size_t)(2 * 16 + hg * 4 + reg) * (COUT * T_N);
        size_t i3 = base + (size_t)(3 * 16 + hg * 4 + reg) * (COUT * T_N);
        outp[i0] = acc0[reg] * inv_n;   // store '='; ifft adds x1 after
        outp[i1] = acc1[reg] * inv_n;
        outp[i2] = acc2[reg] * inv_n;
        outp[i3] = acc3[reg] * inv_n;
    }
}

// ---------------------------------------------------------------------------
// ifft: x1 added on top of x2 (outp already holds x2 contribution).
// ---------------------------------------------------------------------------
__global__ __launch_bounds__(256) void k_ifft(const float2* __restrict__ out1T,
                                              float* __restrict__ outp) {
    __shared__ float2 A[1024];
    __shared__ float2 Bb[1024];
    __shared__ float2 TW[1024];
    int row = blockIdx.x;
    int tid = threadIdx.x;
    build_tw4<1>(TW, tid);
    const float2* src = out1T + (size_t)row * T_N;
#pragma unroll
    for (int r = 0; r < 4; ++r) {
        int j = tid + (r << 8);
        A[j] = src[j];
    }
    float2* R = fft1024_r4<1>(A, Bb, TW, tid);
    float* dst = outp + (size_t)row * T_N;
    const float inv_n = 1.0f / (float)T_N;
#pragma unroll
    for (int r = 0; r < 4; ++r) {
        int j = tid + (r << 8);
        dst[j] += R[j].x * inv_n;
    }
}

// ---------------------------------------------------------------------------
// Layout (ws >= 65MB, proven by R9/R10's active 65MB tier):
//   [0,16M):  alpha -> o2part
//   [16,24M): aThU ; [24,32M): aTlU ; [16,32M) reused as out1T
//   [32M,+):  aXh, aXl, pol4
//   [33,37):  aHi ; [37,41): aLo
//   [41,49):  hw
//   [49,65):  out1tmp
// ---------------------------------------------------------------------------
extern "C" void kernel_launch(void* const* d_in, const int* in_sizes, int n_in,
                              void* d_out, int out_size, void* d_ws, size_t ws_size,
                              hipStream_t stream) {
    const float* x   = (const float*)d_in[0];
    const float* pr  = (const float*)d_in[2];
    const float* pim = (const float*)d_in[3];
    const float* rr  = (const float*)d_in[4];
    const float* ri  = (const float*)d_in[5];
    float* outp = (float*)d_out;

    char* ws = (char*)d_ws;
    const size_t MB = 1024 * 1024;
    const size_t KB = 1024;
    float2*       alpha  = (float2*)ws;                        // [0,16M)
    unsigned int* aThU   = (unsigned int*)(ws + 16 * MB);      // [16,24)
    unsigned int* aTlU   = (unsigned int*)(ws + 24 * MB);      // [24,32)
    short*        aXh    = (short*)(ws + 32 * MB);             // 128K
    short*        aXl    = (short*)(ws + 32 * MB + 128 * KB);  // 128K
    float4*       pol4   = (float4*)(ws + 32 * MB + 512 * KB); // 256K
    short*        aHi    = (short*)(ws + 33 * MB);             // [33,37)
    short*        aLo    = (short*)(ws + 37 * MB);             // [37,41)
    float2*       hw     = (float2*)(ws + 41 * MB);            // [41,49)
    float2*       out1tmp = (float2*)(ws + 49 * MB);           // [49,65)
    float*        o2part  = (float*)ws;                        // alpha dead
    float2*       out1T   = (float2*)(ws + 16 * MB);           // aT dead

    k_fft_fwd     <<<B_N * CIN, 256, 0, stream>>>(x, alpha, aHi, aLo,
                                                  pr, pim, rr, ri, pol4);
    k_thw_out2m   <<<2304, 256, 0, stream>>>(alpha, aThU, aTlU, pol4, hw,
                                             aHi, aLo, pr, pim, rr, ri, o2part);
    k_out1_reduce <<<1088, 256, 0, stream>>>(aThU, aTlU, hw, out1tmp,
                                             (const float4*)o2part,
                                             (short4*)aXh, (short4*)aXl);
    k_to1_x2m     <<<1536, 256, 0, stream>>>(out1tmp, out1T, aXh, aXl,
                                             pr, pim, outp);
    k_ifft        <<<B_N * COUT, 256, 0, stream>>>(out1T, outp);
}

// Round 23
// 110.672 us; speedup vs baseline: 1.2846x; 1.0172x over previous
//
#include <hip/hip_runtime.h>

#define T_N   1024
#define B_N   64
#define CIN   32
#define COUT  32
#define MODES 16
#define DT    0.01f
#define PI_F  3.14159265358979323846f
#define W_SCALE 0.613592315154256f   /* 2*pi/(T_N*DT) */
#define W_NYQ  (-314.1592653589793f) /* -pi/DT */

typedef short bf16x8 __attribute__((ext_vector_type(8)));
typedef float f32x4 __attribute__((ext_vector_type(4)));

__device__ __forceinline__ float fastrcp(float x) {
    float r;
    asm("v_rcp_f32 %0, %1" : "=v"(r) : "v"(x));
    return r;
}

// cheap split: truncate hi, truncate lo (pair error <= 2^-16 rel)
__device__ __forceinline__ void bfsplit(float v, short* ph, short* pl) {
    unsigned int u = __float_as_uint(v);
    float lo = v - __uint_as_float(u & 0xFFFF0000u);
    *ph = (short)(u >> 16);
    *pl = (short)(__float_as_uint(lo) >> 16);
}

// ---------------------------------------------------------------------------
// Radix-4 Stockham FFT, length 1024, 5 stages, LDS twiddle table (1024 ent).
// ---------------------------------------------------------------------------
template <int SIGN>
__device__ __forceinline__ float2* fft1024_r4(float2* A, float2* B,
                                              const float2* TW, int tid) {
    float2* src = A;
    float2* dst = B;
    int m = 1;
#pragma unroll
    for (int s = 0; s < 5; ++s) {
        __syncthreads();
        int k  = tid & (m - 1);
        int jm = tid - k;                       // j*m
        float2 a = src[tid];
        float2 b = src[tid + 256];
        float2 c = src[tid + 512];
        float2 d = src[tid + 768];
        float2 t0 = make_float2(a.x + c.x, a.y + c.y);
        float2 t1 = make_float2(a.x - c.x, a.y - c.y);
        float2 t2 = make_float2(b.x + d.x, b.y + d.y);
        float2 t3 = make_float2(b.x - d.x, b.y - d.y);
        float2 it3 = (SIGN == 1) ? make_float2(-t3.y, t3.x)
                                 : make_float2(t3.y, -t3.x);
        float2 y0 = make_float2(t0.x + t2.x, t0.y + t2.y);
        float2 y2 = make_float2(t0.x - t2.x, t0.y - t2.y);
        float2 y1 = make_float2(t1.x + it3.x, t1.y + it3.y);
        float2 y3 = make_float2(t1.x - it3.x, t1.y - it3.y);
        float2 w1 = TW[jm];
        float2 w2 = TW[2 * jm];
        float2 w3 = TW[3 * jm];
        int ob = k + 4 * jm;
        dst[ob] = y0;
        dst[ob + m]     = make_float2(w1.x * y1.x - w1.y * y1.y,
                                      w1.x * y1.y + w1.y * y1.x);
        dst[ob + 2 * m] = make_float2(w2.x * y2.x - w2.y * y2.y,
                                      w2.x * y2.y + w2.y * y2.x);
        dst[ob + 3 * m] = make_float2(w3.x * y3.x - w3.y * y3.y,
                                      w3.x * y3.y + w3.y * y3.x);
        float2* t = src; src = dst; dst = t;
        m <<= 2;
    }
    __syncthreads();
    return src;
}

template <int SIGN>
__device__ __forceinline__ void build_tw4(float2* TW, int tid) {
#pragma unroll
    for (int r = 0; r < 4; ++r) {
        int a = tid + (r << 8);                 // 0..1023
        float sn, cs;
        __sincosf((float)SIGN * PI_F * (float)a * (1.0f / 512.0f), &sn, &cs);
        TW[a] = make_float2(cs, sn);
    }
}

// ---------------------------------------------------------------------------
// forward FFT + fused split-bf16 conversion + (blocks 0-63) pol4 pack.
// ---------------------------------------------------------------------------
__global__ __launch_bounds__(256) void k_fft_fwd(const float* __restrict__ x,
                                                 float2* __restrict__ alpha,
                                                 short* __restrict__ aHi,
                                                 short* __restrict__ aLo,
                                                 const float* __restrict__ pr,
                                                 const float* __restrict__ pim,
                                                 const float* __restrict__ rr,
                                                 const float* __restrict__ ri,
                                                 float4* __restrict__ pol4) {
    __shared__ float2 A[1024];
    __shared__ float2 Bb[1024];
    __shared__ float2 TW[1024];
    int row = blockIdx.x;
    int tid = threadIdx.x;
    build_tw4<-1>(TW, tid);
    const float* xr = x + (size_t)row * T_N;
#pragma unroll
    for (int r = 0; r < 4; ++r) {
        int j = tid + (r << 8);
        A[j] = make_float2(xr[j], 0.0f);
    }
    float2* R = fft1024_r4<-1>(A, Bb, TW, tid);
    float2* outp = alpha + (size_t)row * T_N;
#pragma unroll
    for (int r = 0; r < 4; ++r) {
        int j = tid + (r << 8);
        outp[j] = R[j];
    }
    size_t base = (size_t)row * 1024;
#pragma unroll
    for (int rr_ = 0; rr_ < 2; ++rr_) {
        int xj = tid + (rr_ << 8);        // 0..511
        float2 v = R[xj];
        float aR = v.x;
        float aI = (xj == 0) ? R[512].x : v.y;
        short h0, l0, h1, l1;
        bfsplit(aR, &h0, &l0);
        bfsplit(aI, &h1, &l1);
        aHi[base + xj * 2]     = h0;
        aHi[base + xj * 2 + 1] = h1;
        aLo[base + xj * 2]     = l0;
        aLo[base + xj * 2 + 1] = l1;
    }
    if (row < 64) {
        int idx = row * 256 + tid;
        pol4[idx] = make_float4(pr[idx], pim[idx], rr[idx], ri[idx]);
    }
}

// ---------------------------------------------------------------------------
// fused triple kernel (register-balanced, T14 A-prefetch in out2m):
//   blocks [0,1024):     transpose alpha -> packed bf16 aT[i][x][b]
//   blocks [1024,1280):  Hw table (streaming pol4, low-VGPR)
//   blocks [1280,2304):  out2 MFMA -> partial[chunk=(i*2+xh)][b][n]
// ---------------------------------------------------------------------------
#define ABROW 40   /* shorts per LDS row: 32 data + 8 pad (80B) */
__global__ __launch_bounds__(256) void k_thw_out2m(const float2* __restrict__ alpha,
                                                   unsigned int* __restrict__ aThU,
                                                   unsigned int* __restrict__ aTlU,
                                                   const float4* __restrict__ pol4,
                                                   float2* __restrict__ hw,
                                                   const short* __restrict__ aHi,
                                                   const short* __restrict__ aLo,
                                                   const float* __restrict__ pr,
                                                   const float* __restrict__ pim,
                                                   const float* __restrict__ rr,
                                                   const float* __restrict__ ri,
                                                   float* __restrict__ partial) {
    __shared__ __align__(16) char SMEM[20992];
    int bid = blockIdx.x;
    int tid = threadIdx.x;

    if (bid < 1024) {
        // ---- transpose path ----
        float2* T = (float2*)SMEM;             // 32*66 float2 = 16896 B
        int i = bid >> 5, xt = bid & 31;
#pragma unroll
        for (int r = 0; r < 8; ++r) {
            int e = tid + (r << 8);
            int xx = e & 31, b = e >> 5;
            T[xx * 66 + b] = alpha[((size_t)(b * CIN + i)) * T_N + xt * 32 + xx];
        }
        __syncthreads();
#pragma unroll
        for (int r = 0; r < 8; ++r) {
            int e = tid + (r << 8);
            int b = e & 63, xx = e >> 6;
            float2 v = T[xx * 66 + b];
            short hR, lR, hI, lI;
            bfsplit(v.x, &hR, &lR);
            bfsplit(v.y, &hI, &lI);
            size_t idx = ((size_t)i * T_N + xt * 32 + xx) * B_N + b;
            aThU[idx] = (unsigned int)(unsigned short)hR |
                        ((unsigned int)(unsigned short)hI << 16);
            aTlU[idx] = (unsigned int)(unsigned short)lR |
                        ((unsigned int)(unsigned short)lI << 16);
        }
        return;
    }
    if (bid < 1280) {
        // ---- Hw path: streaming pol4 (low register footprint) ----
        int xb = bid - 1024;
        int io0 = tid * 4;
        float wv[4];
#pragma unroll
        for (int xi = 0; xi < 4; ++xi) {
            int xg = xb * 4 + xi;
            int fx = xg - ((xg >= 512) ? 1024 : 0);
            wv[xi] = (float)fx * W_SCALE;
        }
        float accR[4][4] = {}, accI[4][4] = {};   // [xi][j]
#pragma unroll
        for (int j = 0; j < 4; ++j) {
            const float4* pp = pol4 + (io0 + j) * 16;
#pragma unroll 1
            for (int k = 0; k < 16; ++k) {
                float4 p = pp[k];
#pragma unroll
                for (int xi = 0; xi < 4; ++xi) {
                    float d = wv[xi] - p.y;
                    float inv = fastrcp(fmaf(d, d, p.x * p.x));
                    float vR = -p.x * inv, vI = -d * inv;
                    accR[xi][j] += p.z * vR - p.w * vI;
                    accI[xi][j] += p.z * vI + p.w * vR;
                }
            }
        }
#pragma unroll
        for (int xi = 0; xi < 4; ++xi) {
            float4* dst = (float4*)(hw + (size_t)(xb * 4 + xi) * 1024 + io0);
            dst[0] = make_float4(accR[xi][0], accI[xi][0], accR[xi][1], accI[xi][1]);
            dst[1] = make_float4(accR[xi][2], accI[xi][2], accR[xi][3], accI[xi][3]);
        }
        return;
    }

    // ---- out2 MFMA path (T14 reg-staged A-prefetch) ----
    short* sAh = (short*)SMEM;                 // 2560 shorts each
    short* sAl = sAh + 64 * ABROW;
    short* sBh = sAl + 64 * ABROW;
    short* sBl = sBh + 64 * ABROW;             // ends at 20480 B
    float* sPol = (float*)(SMEM + 20480);      // 4*32 floats -> 20992 B

    int idx2 = bid - 1280;                     // 0..1023
    const int nb = idx2 & 15, xh = (idx2 >> 4) & 1, i = idx2 >> 5;
    const int w = tid >> 6, l = tid & 63;
    const int r = l & 15, hg = l >> 4;

    if (tid < 32) {
        int o = nb * 2 + (tid >> 4), k = tid & 15;
        int pidx = (i * COUT + o) * MODES + k;
        sPol[0 * 32 + tid] = pr[pidx]; sPol[1 * 32 + tid] = pim[pidx];
        sPol[2 * 32 + tid] = rr[pidx]; sPol[3 * 32 + tid] = ri[pidx];
    }
    __syncthreads();

    f32x4 acc0 = {0.f, 0.f, 0.f, 0.f};
    f32x4 acc1 = {0.f, 0.f, 0.f, 0.f};
    f32x4 acc2 = {0.f, 0.f, 0.f, 0.f};
    f32x4 acc3 = {0.f, 0.f, 0.f, 0.f};

    const int sb = tid >> 2;
    const int sc = (tid & 3) * 8;
    const size_t abase = ((size_t)sb * CIN + i) * 1024 + (size_t)xh * 512;

    const int bn = tid & 63, bh = tid >> 6;
    const int bok = bn >> 1, bcomp = bn & 1;
    const float pa = sPol[0 * 32 + bok], pb = sPol[1 * 32 + bok];
    const float prr_ = sPol[2 * 32 + bok], pri_ = sPol[3 * 32 + bok];
    const float K_d  = pa * pa - pb * pb;
    const float mKe  = -2.0f * pa * pb;
    const float K_e2 = (2.0f * pa * pb) * (2.0f * pa * pb);
    const float prx2 = 2.0f * (pa * prr_ - pb * pri_);
    const float piy2 = 2.0f * (pa * pri_ + pb * prr_);
    const float A1 = bcomp ? piy2 : prx2;
    const float B1 = bcomp ? prx2 : -piy2;
    const float A2 = bcomp ? pri_ : prr_;
    const float B2 = bcomp ? prr_ : -pri_;

    // prologue: prefetch ks=0 A-tile into registers
    float4 rAh = *(const float4*)&aHi[abase + sc];
    float4 rAl = *(const float4*)&aLo[abase + sc];

    for (int ks = 0; ks < 16; ++ks) {
        __syncthreads();                       // prev MFMA reads done
        *(float4*)&sAh[sb * ABROW + sc] = rAh;
        *(float4*)&sAl[sb * ABROW + sc] = rAl;
        {
            bf16x8 vh, vl;
#pragma unroll
            for (int j4 = 0; j4 < 4; ++j4) {
                int xl = bh * 4 + j4;
                int xg = xh * 256 + ks * 16 + xl;
                float v1, v2;
                if (xg == 0) {
                    float s1 = pa * pa + pb * pb;
                    float q1r = pa / s1, q1i = -pb / s1;
                    float c1r = prr_ * q1r - pri_ * q1i;
                    float c1i = prr_ * q1i + pri_ * q1r;
                    float dr = -pa, di = W_NYQ - pb;
                    float s2 = dr * dr + di * di;
                    float q2r = dr / s2, q2i = -di / s2;
                    float c2r = -(prr_ * q2r - pri_ * q2i);
                    float c2i = -(prr_ * q2i + pri_ * q2r);
                    v1 = bcomp ? c1i : c1r;
                    v2 = bcomp ? c2i : c2r;
                } else {
                    float wv = (float)xg * W_SCALE;
                    float denr = fmaf(wv, wv, K_d);
                    float s = fmaf(denr, denr, K_e2);
                    float inv = fastrcp(s);
                    float qr = denr * inv, qi = mKe * inv;
                    v1 = A1 * qr + B1 * qi;
                    float rq = A2 * qr + B2 * qi;
                    v2 = -2.0f * wv * rq;
                }
                short h1, l1, h2, l2;
                bfsplit(v1, &h1, &l1);
                bfsplit(v2, &h2, &l2);
                vh[j4 * 2] = h1; vh[j4 * 2 + 1] = h2;
                vl[j4 * 2] = l1; vl[j4 * 2 + 1] = l2;
            }
            *(bf16x8*)&sBh[bn * ABROW + bh * 8] = vh;
            *(bf16x8*)&sBl[bn * ABROW + bh * 8] = vl;
        }
        if (ks + 1 < 16) {                     // issue next tile's loads early
            rAh = *(const float4*)&aHi[abase + (ks + 1) * 32 + sc];
            rAl = *(const float4*)&aLo[abase + (ks + 1) * 32 + sc];
        }
        __syncthreads();

        bf16x8 bhf = *(bf16x8*)&sBh[(w * 16 + r) * ABROW + hg * 8];
        bf16x8 blf = *(bf16x8*)&sBl[(w * 16 + r) * ABROW + hg * 8];
        {
            bf16x8 ah = *(bf16x8*)&sAh[(0 * 16 + r) * ABROW + hg * 8];
            bf16x8 al = *(bf16x8*)&sAl[(0 * 16 + r) * ABROW + hg * 8];
            acc0 = __builtin_amdgcn_mfma_f32_16x16x32_bf16(ah, bhf, acc0, 0, 0, 0);
            acc0 = __builtin_amdgcn_mfma_f32_16x16x32_bf16(al, bhf, acc0, 0, 0, 0);
            acc0 = __builtin_amdgcn_mfma_f32_16x16x32_bf16(ah, blf, acc0, 0, 0, 0);
        }
        {
            bf16x8 ah = *(bf16x8*)&sAh[(1 * 16 + r) * ABROW + hg * 8];
            bf16x8 al = *(bf16x8*)&sAl[(1 * 16 + r) * ABROW + hg * 8];
            acc1 = __builtin_amdgcn_mfma_f32_16x16x32_bf16(ah, bhf, acc1, 0, 0, 0);
            acc1 = __builtin_amdgcn_mfma_f32_16x16x32_bf16(al, bhf, acc1, 0, 0, 0);
            acc1 = __builtin_amdgcn_mfma_f32_16x16x32_bf16(ah, blf, acc1, 0, 0, 0);
        }
        {
            bf16x8 ah = *(bf16x8*)&sAh[(2 * 16 + r) * ABROW + hg * 8];
            bf16x8 al = *(bf16x8*)&sAl[(2 * 16 + r) * ABROW + hg * 8];
            acc2 = __builtin_amdgcn_mfma_f32_16x16x32_bf16(ah, bhf, acc2, 0, 0, 0);
            acc2 = __builtin_amdgcn_mfma_f32_16x16x32_bf16(al, bhf, acc2, 0, 0, 0);
            acc2 = __builtin_amdgcn_mfma_f32_16x16x32_bf16(ah, blf, acc2, 0, 0, 0);
        }
        {
            bf16x8 ah = *(bf16x8*)&sAh[(3 * 16 + r) * ABROW + hg * 8];
            bf16x8 al = *(bf16x8*)&sAl[(3 * 16 + r) * ABROW + hg * 8];
            acc3 = __builtin_amdgcn_mfma_f32_16x16x32_bf16(ah, bhf, acc3, 0, 0, 0);
            acc3 = __builtin_amdgcn_mfma_f32_16x16x32_bf16(al, bhf, acc3, 0, 0, 0);
            acc3 = __builtin_amdgcn_mfma_f32_16x16x32_bf16(ah, blf, acc3, 0, 0, 0);
        }
    }

    int chunk = i * 2 + xh;
    int n = nb * 64 + w * 16 + r;
    float* dst = partial + (size_t)chunk * (B_N * 1024) + n;
#pragma unroll
    for (int reg = 0; reg < 4; ++reg) {
        dst[(0 * 16 + hg * 4 + reg) * 1024] = acc0[reg];
        dst[(1 * 16 + hg * 4 + reg) * 1024] = acc1[reg];
        dst[(2 * 16 + hg * 4 + reg) * 1024] = acc2[reg];
        dst[(3 * 16 + hg * 4 + reg) * 1024] = acc3[reg];
    }
}

// ---------------------------------------------------------------------------
// fused: blocks [0,1024): out1 (alpha-slice MAC vs hw row)
//        blocks [1024,1088): reduce 64 partials -> split-bf16 aXh/aXl
// ---------------------------------------------------------------------------
__global__ __launch_bounds__(256) void k_out1_reduce(const unsigned int* __restrict__ aThU,
                                                     const unsigned int* __restrict__ aTlU,
                                                     const float2* __restrict__ hw,
                                                     float2* __restrict__ out1tmp,
                                                     const float4* __restrict__ p,
                                                     short4* __restrict__ aXh,
                                                     short4* __restrict__ aXl) {
    __shared__ float sARe[32 * 64];
    __shared__ float sAIm[32 * 64];
    int bid = blockIdx.x;
    int tid = threadIdx.x;
    if (bid >= 1024) {
        int f = (bid - 1024) * 256 + tid;      // 16384 float4s
        float4 s = make_float4(0.f, 0.f, 0.f, 0.f);
        for (int c = 0; c < 64; ++c) {
            float4 v = p[(size_t)c * 16384 + f];
            s.x += v.x; s.y += v.y; s.z += v.z; s.w += v.w;
        }
        short4 h, l;
        bfsplit(s.x, &h.x, &l.x);
        bfsplit(s.y, &h.y, &l.y);
        bfsplit(s.z, &h.z, &l.z);
        bfsplit(s.w, &h.w, &l.w);
        aXh[f] = h;
        aXl[f] = l;
        return;
    }
    int x = bid;
#pragma unroll
    for (int r = 0; r < 4; ++r) {
        int e = tid + (r << 8);
        int i = e >> 5, bp = e & 31;
        size_t base = ((size_t)i * T_N + x) * B_N + bp * 2;
        uint2 uh = *(const uint2*)&aThU[base];
        uint2 ul = *(const uint2*)&aTlU[base];
        float r0 = __uint_as_float(uh.x << 16) + __uint_as_float(ul.x << 16);
        float i0 = __uint_as_float(uh.x & 0xFFFF0000u) + __uint_as_float(ul.x & 0xFFFF0000u);
        float r1 = __uint_as_float(uh.y << 16) + __uint_as_float(ul.y << 16);
        float i1 = __uint_as_float(uh.y & 0xFFFF0000u) + __uint_as_float(ul.y & 0xFFFF0000u);
        *(float2*)&sARe[i * 64 + bp * 2] = make_float2(r0, r1);
        *(float2*)&sAIm[i * 64 + bp * 2] = make_float2(i0, i1);
    }
    __syncthreads();

    int o = tid & 31, bg = tid >> 5;
    const float2* hrow = hw + (size_t)x * 1024 + o;
    float accR[8] = {}, accI[8] = {};
#pragma unroll 4
    for (int i = 0; i < CIN; ++i) {
        float2 h = hrow[i * 32];
        float4 ar0 = *(const float4*)&sARe[i * 64 + bg * 8];
        float4 ar1 = *(const float4*)&sARe[i * 64 + bg * 8 + 4];
        float4 ai0 = *(const float4*)&sAIm[i * 64 + bg * 8];
        float4 ai1 = *(const float4*)&sAIm[i * 64 + bg * 8 + 4];
        float aR[8] = {ar0.x, ar0.y, ar0.z, ar0.w, ar1.x, ar1.y, ar1.z, ar1.w};
        float aI[8] = {ai0.x, ai0.y, ai0.z, ai0.w, ai1.x, ai1.y, ai1.z, ai1.w};
#pragma unroll
        for (int bb = 0; bb < 8; ++bb) {
            accR[bb] += aR[bb] * h.x - aI[bb] * h.y;
            accI[bb] += aR[bb] * h.y + aI[bb] * h.x;
        }
    }
#pragma unroll
    for (int bb = 0; bb < 8; ++bb) {
        out1tmp[(size_t)x * 2048 + (bg * 8 + bb) * 32 + o] =
            make_float2(accR[bb], accI[bb]);
    }
}

// ---------------------------------------------------------------------------
// fused: blocks [0,1024): transpose out1tmp[x][bo] -> out1T[bo][x]
//        blocks [1024,1536): x2m (T14 A-prefetch; stores '=' into outp)
// ---------------------------------------------------------------------------
__global__ __launch_bounds__(256) void k_to1_x2m(const float2* __restrict__ out1tmp,
                                                 float2* __restrict__ out1T,
                                                 const short* __restrict__ aXhS,
                                                 const short* __restrict__ aXlS,
                                                 const float* __restrict__ pr,
                                                 const float* __restrict__ pim,
                                                 float* __restrict__ outp) {
    __shared__ __align__(16) char SMEM[24576];
    int bid = blockIdx.x;
    int tid = threadIdx.x;

    if (bid < 1024) {
        float2* T = (float2*)SMEM;             // 64*33 float2 = 16896 B
        int bot = bid >> 5, xt = bid & 31;
#pragma unroll
        for (int r = 0; r < 8; ++r) {
            int e = tid + (r << 8);
            int j = e & 63, xr = e >> 6;
            T[j * 33 + xr] = out1tmp[((size_t)(xt * 32 + xr)) * 2048 + bot * 64 + j];
        }
        __syncthreads();
#pragma unroll
        for (int r = 0; r < 8; ++r) {
            int e = tid + (r << 8);
            int xx = e & 31, j = e >> 5;
            out1T[((size_t)(bot * 64 + j)) * T_N + xt * 32 + xx] = T[j * 33 + xx];
        }
        return;
    }

    short* sAh = (short*)SMEM;
    short* sAl = sAh + 64 * ABROW;
    short* sBh = sAl + 64 * ABROW;
    short* sBl = sBh + 64 * ABROW;
    float* s_pr = (float*)(SMEM + 20480);
    float* s_pim = s_pr + 512;

    int zz = bid - 1024;
    const int zb = zz & 15, o = zz >> 4;
    const int w = tid >> 6, l = tid & 63;
    const int r = l & 15, hg = l >> 4;

#pragma unroll
    for (int rr_ = 0; rr_ < 2; ++rr_) {
        int cm = tid + (rr_ << 8);
        int c = cm >> 4, m = cm & 15;
        int pidx = (c * COUT + o) * MODES + m;
        s_pr[cm] = pr[pidx];
        s_pim[cm] = pim[pidx];
    }
    __syncthreads();

    f32x4 acc0 = {0.f, 0.f, 0.f, 0.f};
    f32x4 acc1 = {0.f, 0.f, 0.f, 0.f};
    f32x4 acc2 = {0.f, 0.f, 0.f, 0.f};
    f32x4 acc3 = {0.f, 0.f, 0.f, 0.f};

    const int sb = tid >> 2;
    const int sc = (tid & 3) * 8;
    const float z0f = (float)(zb * 64);

    const int bz = tid & 63, bh = tid >> 6;
    const float tz = (z0f + (float)bz) * DT;

    // prologue: prefetch ks=0 A-tile
    float4 rAh = *(const float4*)&aXhS[sb * 1024 + sc];
    float4 rAl = *(const float4*)&aXlS[sb * 1024 + sc];

    for (int ks = 0; ks < 32; ++ks) {
        __syncthreads();
        *(float4*)&sAh[sb * ABROW + sc] = rAh;
        *(float4*)&sAl[sb * ABROW + sc] = rAl;
        {
            bf16x8 vh, vl;
#pragma unroll
            for (int j4 = 0; j4 < 4; ++j4) {
                int cml = bh * 4 + j4;
                int cm = ks * 16 + cml;
                float gr = s_pr[cm], gi = s_pim[cm];
                float er = __expf(gr * tz);
                float sn, cn;
                __sincosf(gi * tz, &sn, &cn);
                short h1, l1, h2, l2;
                bfsplit(er * cn,  &h1, &l1);
                bfsplit(-er * sn, &h2, &l2);
                vh[j4 * 2] = h1; vh[j4 * 2 + 1] = h2;
                vl[j4 * 2] = l1; vl[j4 * 2 + 1] = l2;
            }
            *(bf16x8*)&sBh[bz * ABROW + bh * 8] = vh;
            *(bf16x8*)&sBl[bz * ABROW + bh * 8] = vl;
        }
        if (ks + 1 < 32) {                     // issue next tile's loads early
            rAh = *(const float4*)&aXhS[sb * 1024 + (ks + 1) * 32 + sc];
            rAl = *(const float4*)&aXlS[sb * 1024 + (ks + 1) * 32 + sc];
        }
        __syncthreads();

        bf16x8 bhf = *(bf16x8*)&sBh[(w * 16 + r) * ABROW + hg * 8];
        bf16x8 blf = *(bf16x8*)&sBl[(w * 16 + r) * ABROW + hg * 8];
        {
            bf16x8 ah = *(bf16x8*)&sAh[(0 * 16 + r) * ABROW + hg * 8];
            bf16x8 al = *(bf16x8*)&sAl[(0 * 16 + r) * ABROW + hg * 8];
            acc0 = __builtin_amdgcn_mfma_f32_16x16x32_bf16(ah, bhf, acc0, 0, 0, 0);
            acc0 = __builtin_amdgcn_mfma_f32_16x16x32_bf16(al, bhf, acc0, 0, 0, 0);
            acc0 = __builtin_amdgcn_mfma_f32_16x16x32_bf16(ah, blf, acc0, 0, 0, 0);
        }
        {
            bf16x8 ah = *(bf16x8*)&sAh[(1 * 16 + r) * ABROW + hg * 8];
            bf16x8 al = *(bf16x8*)&sAl[(1 * 16 + r) * ABROW + hg * 8];
            acc1 = __builtin_amdgcn_mfma_f32_16x16x32_bf16(ah, bhf, acc1, 0, 0, 0);
            acc1 = __builtin_amdgcn_mfma_f32_16x16x32_bf16(al, bhf, acc1, 0, 0, 0);
            acc1 = __builtin_amdgcn_mfma_f32_16x16x32_bf16(ah, blf, acc1, 0, 0, 0);
        }
        {
            bf16x8 ah = *(bf16x8*)&sAh[(2 * 16 + r) * ABROW + hg * 8];
            bf16x8 al = *(bf16x8*)&sAl[(2 * 16 + r) * ABROW + hg * 8];
            acc2 = __builtin_amdgcn_mfma_f32_16x16x32_bf16(ah, bhf, acc2, 0, 0, 0);
            acc2 = __builtin_amdgcn_mfma_f32_16x16x32_bf16(al, bhf, acc2, 0, 0, 0);
            acc2 = __builtin_amdgcn_mfma_f32_16x16x32_bf16(ah, blf, acc2, 0, 0, 0);
        }
        {
            bf16x8 ah = *(bf16x8*)&sAh[(3 * 16 + r) * ABROW + hg * 8];
            bf16x8 al = *(bf16x8*)&sAl[(3 * 16 + r) * ABROW + hg * 8];
            acc3 = __builtin_amdgcn_mfma_f32_16x16x32_bf16(ah, bhf, acc3, 0, 0, 0);
            acc3 = __builtin_amdgcn_mfma_f32_16x16x32_bf16(al, bhf, acc3, 0, 0, 0);
            acc3 = __builtin_amdgcn_mfma_f32_16x16x32_bf16(ah, blf, acc3, 0, 0, 0);
        }
    }

    const float inv_n = 1.0f / (float)T_N;
    size_t base = (size_t)o * T_N + zb * 64 + w * 16 + r;
#pragma unroll
    for (int reg = 0; reg < 4; ++reg) {
        size_t i0 = base + (size_t)(0 * 16 + hg * 4 + reg) * (COUT * T_N);
        size_t i1 = base + (size_t)(1 * 16 + hg * 4 + reg) * (COUT * T_N);
        size_t i2 = base + (size_t)(2 * 16 + hg * 4 + reg) * (COUT * T_N);
        size_t i3 = base + (size_t)(3 * 16 + hg * 4 + reg) * (COUT * T_N);
        outp[i0] = acc0[reg] * inv_n;   // store '='; ifft adds x1 after
        outp[i1] = acc1[reg] * inv_n;
        outp[i2] = acc2[reg] * inv_n;
        outp[i3] = acc3[reg] * inv_n;
    }
}

// ---------------------------------------------------------------------------
// ifft: x1 added on top of x2 (outp already holds x2 contribution).
// ---------------------------------------------------------------------------
__global__ __launch_bounds__(256) void k_ifft(const float2* __restrict__ out1T,
                                              float* __restrict__ outp) {
    __shared__ float2 A[1024];
    __shared__ float2 Bb[1024];
    __shared__ float2 TW[1024];
    int row = blockIdx.x;
    int tid = threadIdx.x;
    build_tw4<1>(TW, tid);
    const float2* src = out1T + (size_t)row * T_N;
#pragma unroll
    for (int r = 0; r < 4; ++r) {
        int j = tid + (r << 8);
        A[j] = src[j];
    }
    float2* R = fft1024_r4<1>(A, Bb, TW, tid);
    float* dst = outp + (size_t)row * T_N;
    const float inv_n = 1.0f / (float)T_N;
#pragma unroll
    for (int r = 0; r < 4; ++r) {
        int j = tid + (r << 8);
        dst[j] += R[j].x * inv_n;
    }
}

// ---------------------------------------------------------------------------
// Layout (ws >= 65MB, proven by R9/R10's active 65MB tier):
//   [0,16M):  alpha -> o2part
//   [16,24M): aThU ; [24,32M): aTlU ; [16,32M) reused as out1T
//   [32M,+):  aXh, aXl, pol4
//   [33,37):  aHi ; [37,41): aLo
//   [41,49):  hw
//   [49,65):  out1tmp
// ---------------------------------------------------------------------------
extern "C" void kernel_launch(void* const* d_in, const int* in_sizes, int n_in,
                              void* d_out, int out_size, void* d_ws, size_t ws_size,
                              hipStream_t stream) {
    const float* x   = (const float*)d_in[0];
    const float* pr  = (const float*)d_in[2];
    const float* pim = (const float*)d_in[3];
    const float* rr  = (const float*)d_in[4];
    const float* ri  = (const float*)d_in[5];
    float* outp = (float*)d_out;

    char* ws = (char*)d_ws;
    const size_t MB = 1024 * 1024;
    const size_t KB = 1024;
    float2*       alpha  = (float2*)ws;                        // [0,16M)
    unsigned int* aThU   = (unsigned int*)(ws + 16 * MB);      // [16,24)
    unsigned int* aTlU   = (unsigned int*)(ws + 24 * MB);      // [24,32)
    short*        aXh    = (short*)(ws + 32 * MB);             // 128K
    short*        aXl    = (short*)(ws + 32 * MB + 128 * KB);  // 128K
    float4*       pol4   = (float4*)(ws + 32 * MB + 512 * KB); // 256K
    short*        aHi    = (short*)(ws + 33 * MB);             // [33,37)
    short*        aLo    = (short*)(ws + 37 * MB);             // [37,41)
    float2*       hw     = (float2*)(ws + 41 * MB);            // [41,49)
    float2*       out1tmp = (float2*)(ws + 49 * MB);           // [49,65)
    float*        o2part  = (float*)ws;                        // alpha dead
    float2*       out1T   = (float2*)(ws + 16 * MB);           // aT dead

    k_fft_fwd     <<<B_N * CIN, 256, 0, stream>>>(x, alpha, aHi, aLo,
                                                  pr, pim, rr, ri, pol4);
    k_thw_out2m   <<<2304, 256, 0, stream>>>(alpha, aThU, aTlU, pol4, hw,
                                             aHi, aLo, pr, pim, rr, ri, o2part);
    k_out1_reduce <<<1088, 256, 0, stream>>>(aThU, aTlU, hw, out1tmp,
                                             (const float4*)o2part,
                                             (short4*)aXh, (short4*)aXl);
    k_to1_x2m     <<<1536, 256, 0, stream>>>(out1tmp, out1T, aXh, aXl,
                                             pr, pim, outp);
    k_ifft        <<<B_N * COUT, 256, 0, stream>>>(out1T, outp);
}